// Round 1
// baseline (554.609 us; speedup 1.0000x reference)
//
#include <hip/hip_runtime.h>
#include <cstdint>
#include <cstddef>

#define NN 100000
#define NE 1600000
#define DIM 256

// workspace layout (ints)
#define NA 100352            // NN rounded up, 4B ints
#define CSR_IOFF (4*NA + 512)
// byte offsets for bf16 regions
#define HS_OFF   8007680ull                     // (CSR_IOFF + NE) * 4
#define WT_OFF   (HS_OFF + (size_t)NN*DIM*2)    // 59,207,680
#define AGG_OFF  (WT_OFF + (size_t)DIM*DIM*2)   // 59,338,752
#define WS_NEED  (AGG_OFF + (size_t)NN*DIM*2)   // 110,538,752

typedef short bf16x8 __attribute__((ext_vector_type(8)));
typedef float f32x4 __attribute__((ext_vector_type(4)));

__device__ __forceinline__ float bf2f(unsigned short u) {
    return __uint_as_float(((unsigned)u) << 16);
}
__device__ __forceinline__ unsigned short f2bf(float f) {
    unsigned u = __float_as_uint(f);
    u += 0x7FFF + ((u >> 16) & 1);   // round-to-nearest-even
    return (unsigned short)(u >> 16);
}

// ---- degree histograms -----------------------------------------------------
__global__ void k_deg(const int* __restrict__ src, const int* __restrict__ dst,
                      int* __restrict__ outd, int* __restrict__ ind) {
    int e = blockIdx.x * blockDim.x + threadIdx.x;
    if (e < NE) {
        atomicAdd(&outd[src[e]], 1);
        atomicAdd(&ind[dst[e]], 1);
    }
}

// ---- 3-kernel exclusive prefix scan of in_deg -> row_ptr -------------------
#define SCAN_NB 98   // ceil(NN/1024)

__global__ void k_scan1(const int* __restrict__ ind, int* __restrict__ rowp,
                        int* __restrict__ bsum) {
    __shared__ int tmp[1024];
    int t = threadIdx.x;
    int i = blockIdx.x * 1024 + t;
    int x = (i < NN) ? ind[i] : 0;
    tmp[t] = x;
    __syncthreads();
    for (int off = 1; off < 1024; off <<= 1) {
        int v = (t >= off) ? tmp[t - off] : 0;
        __syncthreads();
        tmp[t] += v;
        __syncthreads();
    }
    if (i < NN) rowp[i] = tmp[t] - x;           // exclusive within block
    if (t == 1023) bsum[blockIdx.x] = tmp[t];   // block total
}

__global__ void k_scan2(int* __restrict__ bsum) {
    __shared__ int tmp[128];
    int t = threadIdx.x;
    int x = (t < SCAN_NB) ? bsum[t] : 0;
    tmp[t] = x;
    __syncthreads();
    for (int off = 1; off < 128; off <<= 1) {
        int v = (t >= off) ? tmp[t - off] : 0;
        __syncthreads();
        tmp[t] += v;
        __syncthreads();
    }
    if (t < SCAN_NB) bsum[t] = tmp[t] - x;      // exclusive
}

__global__ void k_scan3(int* __restrict__ rowp, const int* __restrict__ bsum) {
    int i = blockIdx.x * 1024 + threadIdx.x;
    if (i < NN) rowp[i] += bsum[blockIdx.x];
    if (i == 0) rowp[NN] = NE;
}

// ---- CSR fill (sorted-by-dst edge array of src indices) --------------------
__global__ void k_fill(const int* __restrict__ src, const int* __restrict__ dst,
                       const int* __restrict__ rowp, int* __restrict__ cnt,
                       int* __restrict__ csr) {
    int e = blockIdx.x * blockDim.x + threadIdx.x;
    if (e < NE) {
        int d = dst[e];
        int p = rowp[d] + atomicAdd(&cnt[d], 1);
        csr[p] = src[e];
    }
}

// ---- h_scaled = bf16(h * rsqrt(max(out_deg,1))) ----------------------------
__global__ void k_hscale(const float* __restrict__ h, const int* __restrict__ outd,
                         unsigned short* __restrict__ hs) {
    int i = blockIdx.x * blockDim.x + threadIdx.x;   // chunk of 4 floats
    if (i >= NN * (DIM / 4)) return;
    int node = i >> 6;                                // DIM/4 = 64 chunks/node
    float s = rsqrtf(fmaxf((float)outd[node], 1.0f));
    float4 v = ((const float4*)h)[i];
    ushort4 o;
    o.x = f2bf(v.x * s);
    o.y = f2bf(v.y * s);
    o.z = f2bf(v.z * s);
    o.w = f2bf(v.w * s);
    ((ushort4*)hs)[i] = o;
}

// ---- weight transpose + bf16: Wt[n][k] = bf16(W[k][n]) ---------------------
__global__ void k_wt(const float* __restrict__ W, unsigned short* __restrict__ wt) {
    int k = blockIdx.x;
    int n = threadIdx.x;
    wt[n * DIM + k] = f2bf(W[k * DIM + n]);
}

// ---- pull aggregation: agg[n] = bf16(norm_dst[n] * sum_e hs[src_e]) --------
__global__ __launch_bounds__(256) void k_agg(const unsigned short* __restrict__ hs,
                                             const int* __restrict__ csr,
                                             const int* __restrict__ rowp,
                                             const int* __restrict__ ind,
                                             unsigned short* __restrict__ agg) {
    int wave = threadIdx.x >> 6;
    int lane = threadIdx.x & 63;
    int node = blockIdx.x * 4 + wave;
    if (node >= NN) return;
    int e0 = rowp[node], e1 = rowp[node + 1];
    float a0 = 0.f, a1 = 0.f, a2 = 0.f, a3 = 0.f;
    int e = e0;
    for (; e + 1 < e1; e += 2) {
        int s0 = csr[e], s1 = csr[e + 1];
        ushort4 u = ((const ushort4*)(hs + (size_t)s0 * DIM))[lane];
        ushort4 v = ((const ushort4*)(hs + (size_t)s1 * DIM))[lane];
        a0 += bf2f(u.x) + bf2f(v.x);
        a1 += bf2f(u.y) + bf2f(v.y);
        a2 += bf2f(u.z) + bf2f(v.z);
        a3 += bf2f(u.w) + bf2f(v.w);
    }
    if (e < e1) {
        int s0 = csr[e];
        ushort4 u = ((const ushort4*)(hs + (size_t)s0 * DIM))[lane];
        a0 += bf2f(u.x);
        a1 += bf2f(u.y);
        a2 += bf2f(u.z);
        a3 += bf2f(u.w);
    }
    float nd = rsqrtf(fmaxf((float)ind[node], 1.0f));
    ushort4 o;
    o.x = f2bf(a0 * nd);
    o.y = f2bf(a1 * nd);
    o.z = f2bf(a2 * nd);
    o.w = f2bf(a3 * nd);
    ((ushort4*)(agg + (size_t)node * DIM))[lane] = o;
}

// ---- GEMM: out = ELU(agg @ W + bias), A bf16 [M,256], Wt bf16 [256][256] ---
// per block: 4 waves, 64 rows; per wave: 16 rows x 256 cols
__global__ __launch_bounds__(256) void k_gemm(const unsigned short* __restrict__ A,
                                              const unsigned short* __restrict__ wt,
                                              const float* __restrict__ bias,
                                              float* __restrict__ out) {
    int wave = threadIdx.x >> 6;
    int lane = threadIdx.x & 63;
    int mbase = blockIdx.x * 64 + wave * 16;
    int fidx = lane & 15;     // A-row / B-col / C-col index within fragment
    int kgrp = lane >> 4;     // k-group 0..3

    int m = mbase + fidx;
    const short* Arow = (const short*)A + (size_t)(m < NN ? m : 0) * DIM;

    f32x4 acc[16];
#pragma unroll
    for (int t = 0; t < 16; ++t) acc[t] = (f32x4){0.f, 0.f, 0.f, 0.f};

    for (int k0 = 0; k0 < DIM; k0 += 32) {
        int kk = k0 + kgrp * 8;
        bf16x8 af = *(const bf16x8*)(Arow + kk);
#pragma unroll
        for (int t = 0; t < 16; ++t) {
            const short* Bp = (const short*)wt + (size_t)(t * 16 + fidx) * DIM + kk;
            bf16x8 bf = *(const bf16x8*)Bp;
            acc[t] = __builtin_amdgcn_mfma_f32_16x16x32_bf16(af, bf, acc[t], 0, 0, 0);
        }
    }

    int rbase = mbase + kgrp * 4;
#pragma unroll
    for (int t = 0; t < 16; ++t) {
        int col = t * 16 + fidx;
        float b = bias[col];
#pragma unroll
        for (int i = 0; i < 4; ++i) {
            int row = rbase + i;
            if (row < NN) {
                float v = acc[t][i] + b;
                out[(size_t)row * DIM + col] = v > 0.f ? v : expm1f(v);
            }
        }
    }
}

extern "C" void kernel_launch(void* const* d_in, const int* in_sizes, int n_in,
                              void* d_out, int out_size, void* d_ws, size_t ws_size,
                              hipStream_t stream) {
    const float* h    = (const float*)d_in[0];
    const float* W    = (const float*)d_in[1];
    const float* bias = (const float*)d_in[2];
    const int*   src  = (const int*)d_in[3];
    const int*   dst  = (const int*)d_in[4];
    float* out = (float*)d_out;

    if (ws_size < WS_NEED) return;  // insufficient scratch -> loud failure

    char* w = (char*)d_ws;
    int* outd = (int*)w;
    int* ind  = outd + NA;
    int* rowp = outd + 2 * NA;
    int* cnt  = outd + 3 * NA;
    int* bsum = outd + 4 * NA;
    int* csr  = outd + CSR_IOFF;
    unsigned short* hs  = (unsigned short*)(w + HS_OFF);
    unsigned short* wt  = (unsigned short*)(w + WT_OFF);
    unsigned short* agg = (unsigned short*)(w + AGG_OFF);

    hipMemsetAsync(outd, 0, (size_t)2 * NA * sizeof(int), stream);  // outd+ind
    hipMemsetAsync(cnt, 0, (size_t)NA * sizeof(int), stream);

    k_deg<<<NE / 256, 256, 0, stream>>>(src, dst, outd, ind);
    k_scan1<<<SCAN_NB, 1024, 0, stream>>>(ind, rowp, bsum);
    k_scan2<<<1, 128, 0, stream>>>(bsum);
    k_scan3<<<SCAN_NB, 1024, 0, stream>>>(rowp, bsum);
    k_fill<<<NE / 256, 256, 0, stream>>>(src, dst, rowp, cnt, csr);
    k_hscale<<<(NN * (DIM / 4)) / 256, 256, 0, stream>>>(h, outd, hs);
    k_wt<<<DIM, DIM, 0, stream>>>(W, wt);
    k_agg<<<(NN + 3) / 4, 256, 0, stream>>>(hs, csr, rowp, ind, agg);
    k_gemm<<<(NN + 63) / 64, 256, 0, stream>>>(agg, wt, bias, out);
}

// Round 4
// 484.660 us; speedup vs baseline: 1.1443x; 1.1443x over previous
//
#include <hip/hip_runtime.h>
#include <cstdint>
#include <cstddef>

#define NN 100000
#define NE 1600000
#define DIM 256

// workspace layout (ints)
#define NA 100352            // NN rounded up, 4B ints
#define CSR_IOFF (4*NA + 512)
// byte offsets for bf16 regions
#define HS_OFF   8007680ull                     // (CSR_IOFF + NE) * 4
#define WT_OFF   (HS_OFF + (size_t)NN*DIM*2)    // weight packed, 128 KB
#define AGG_OFF  (WT_OFF + (size_t)DIM*DIM*2)   // A fragment-packed, 51.2 MB
#define WS_NEED  (AGG_OFF + (size_t)NN*DIM*2)

typedef short bf16x8 __attribute__((ext_vector_type(8)));
typedef float f32x4 __attribute__((ext_vector_type(4)));

__device__ __forceinline__ float bf2f(unsigned short u) {
    return __uint_as_float(((unsigned)u) << 16);
}
__device__ __forceinline__ unsigned short f2bf(float f) {
    unsigned u = __float_as_uint(f);
    u += 0x7FFF + ((u >> 16) & 1);   // round-to-nearest-even
    return (unsigned short)(u >> 16);
}

// ---- degree histograms -----------------------------------------------------
__global__ void k_deg(const int* __restrict__ src, const int* __restrict__ dst,
                      int* __restrict__ outd, int* __restrict__ ind) {
    int e = blockIdx.x * blockDim.x + threadIdx.x;
    if (e < NE) {
        atomicAdd(&outd[src[e]], 1);
        atomicAdd(&ind[dst[e]], 1);
    }
}

// ---- 3-kernel exclusive prefix scan of in_deg -> row_ptr -------------------
#define SCAN_NB 98   // ceil(NN/1024)

__global__ void k_scan1(const int* __restrict__ ind, int* __restrict__ rowp,
                        int* __restrict__ bsum) {
    __shared__ int tmp[1024];
    int t = threadIdx.x;
    int i = blockIdx.x * 1024 + t;
    int x = (i < NN) ? ind[i] : 0;
    tmp[t] = x;
    __syncthreads();
    for (int off = 1; off < 1024; off <<= 1) {
        int v = (t >= off) ? tmp[t - off] : 0;
        __syncthreads();
        tmp[t] += v;
        __syncthreads();
    }
    if (i < NN) rowp[i] = tmp[t] - x;           // exclusive within block
    if (t == 1023) bsum[blockIdx.x] = tmp[t];   // block total
}

__global__ void k_scan2(int* __restrict__ bsum) {
    __shared__ int tmp[128];
    int t = threadIdx.x;
    int x = (t < SCAN_NB) ? bsum[t] : 0;
    tmp[t] = x;
    __syncthreads();
    for (int off = 1; off < 128; off <<= 1) {
        int v = (t >= off) ? tmp[t - off] : 0;
        __syncthreads();
        tmp[t] += v;
        __syncthreads();
    }
    if (t < SCAN_NB) bsum[t] = tmp[t] - x;      // exclusive
}

__global__ void k_scan3(int* __restrict__ rowp, const int* __restrict__ bsum) {
    int i = blockIdx.x * 1024 + threadIdx.x;
    if (i < NN) rowp[i] += bsum[blockIdx.x];
    if (i == 0) rowp[NN] = NE;
}

// ---- CSR fill (sorted-by-dst edge array of src indices) --------------------
__global__ void k_fill(const int* __restrict__ src, const int* __restrict__ dst,
                       const int* __restrict__ rowp, int* __restrict__ cnt,
                       int* __restrict__ csr) {
    int e = blockIdx.x * blockDim.x + threadIdx.x;
    if (e < NE) {
        int d = dst[e];
        int p = rowp[d] + atomicAdd(&cnt[d], 1);
        csr[p] = src[e];
    }
}

// ---- h_scaled = bf16(h * rsqrt(max(out_deg,1))) ----------------------------
__global__ void k_hscale(const float* __restrict__ h, const int* __restrict__ outd,
                         unsigned short* __restrict__ hs) {
    int i = blockIdx.x * blockDim.x + threadIdx.x;   // chunk of 4 floats
    if (i >= NN * (DIM / 4)) return;
    int node = i >> 6;                                // DIM/4 = 64 chunks/node
    float s = rsqrtf(fmaxf((float)outd[node], 1.0f));
    float4 v = ((const float4*)h)[i];
    ushort4 o;
    o.x = f2bf(v.x * s);
    o.y = f2bf(v.y * s);
    o.z = f2bf(v.z * s);
    o.w = f2bf(v.w * s);
    ((ushort4*)hs)[i] = o;
}

// ---- weight -> bf16, MFMA-fragment-packed ----------------------------------
// wtp element p: j=p&7, l=(p>>3)&63, t=(p>>9)&15, ks=p>>13
//   holds W[k = ks*32 + (l>>4)*8 + j][col = t*16 + (l&15)]
__global__ void k_wt2(const float* __restrict__ W, unsigned short* __restrict__ wtp) {
    int p = blockIdx.x * blockDim.x + threadIdx.x;   // 0..65535
    int j = p & 7, l = (p >> 3) & 63, t = (p >> 9) & 15, ks = p >> 13;
    int k = ks * 32 + (l >> 4) * 8 + j;
    int col = t * 16 + (l & 15);
    wtp[p] = f2bf(W[k * DIM + col]);
}

// ---- pull aggregation -> A written MFMA-fragment-packed --------------------
// Ap frag (g, ks) at elements (g*8+ks)*512; lane l holds
//   A[row = g*16 + (l&15)][k = ks*32 + (l>>4)*8 + j], j=0..7
__global__ __launch_bounds__(256) void k_agg(const unsigned short* __restrict__ hs,
                                             const int* __restrict__ csr,
                                             const int* __restrict__ rowp,
                                             const int* __restrict__ ind,
                                             unsigned short* __restrict__ Ap) {
    int wave = threadIdx.x >> 6;
    int lane = threadIdx.x & 63;
    int node = blockIdx.x * 4 + wave;
    if (node >= NN) return;
    int e0 = rowp[node], e1 = rowp[node + 1];
    float a0 = 0.f, a1 = 0.f, a2 = 0.f, a3 = 0.f;
    int e = e0;
    for (; e + 1 < e1; e += 2) {
        int s0 = csr[e], s1 = csr[e + 1];
        ushort4 u = ((const ushort4*)(hs + (size_t)s0 * DIM))[lane];
        ushort4 v = ((const ushort4*)(hs + (size_t)s1 * DIM))[lane];
        a0 += bf2f(u.x) + bf2f(v.x);
        a1 += bf2f(u.y) + bf2f(v.y);
        a2 += bf2f(u.z) + bf2f(v.z);
        a3 += bf2f(u.w) + bf2f(v.w);
    }
    if (e < e1) {
        int s0 = csr[e];
        ushort4 u = ((const ushort4*)(hs + (size_t)s0 * DIM))[lane];
        a0 += bf2f(u.x);
        a1 += bf2f(u.y);
        a2 += bf2f(u.z);
        a3 += bf2f(u.w);
    }
    float nd = rsqrtf(fmaxf((float)ind[node], 1.0f));
    ushort4 o;
    o.x = f2bf(a0 * nd);
    o.y = f2bf(a1 * nd);
    o.z = f2bf(a2 * nd);
    o.w = f2bf(a3 * nd);
    // fragment-packed scatter: this lane's 4 elements are k = 4*lane .. 4*lane+3
    int g = node >> 4, fidx = node & 15;
    int ks = lane >> 3;              // (4*lane)>>5
    int kgrp = (lane >> 1) & 3;      // ((4*lane)&31)>>3
    int j0 = (lane & 1) * 4;         // (4*lane)&7
    size_t pidx = ((size_t)(g * 8 + ks) * 64 + kgrp * 16 + fidx) * 8 + j0;
    *(ushort4*)(Ap + pidx) = o;
}

// ---- GEMM: out = ELU(Ap @ Bp + bias), both operands fragment-packed --------
// 1 wave = 32 rows (2 frag-groups) x 256 cols; 256 MFMA; all loads coalesced.
__global__ __launch_bounds__(256) void k_gemm(const unsigned short* __restrict__ Ap,
                                              const unsigned short* __restrict__ Bp,
                                              const float* __restrict__ bias,
                                              float* __restrict__ out) {
    int wave = threadIdx.x >> 6;
    int lane = threadIdx.x & 63;
    int wg = blockIdx.x * 4 + wave;          // 32-row group id
    if (wg >= NN / 32) return;               // 3125 groups exactly

    const short* A0 = (const short*)Ap + (size_t)wg * 8192 + lane * 8;  // g = 2*wg
    const short* A1 = A0 + 4096;                                        // g = 2*wg+1
    const short* B  = (const short*)Bp + lane * 8;

    f32x4 acc0[16], acc1[16];
#pragma unroll
    for (int t = 0; t < 16; ++t) {
        acc0[t] = (f32x4){0.f, 0.f, 0.f, 0.f};
        acc1[t] = (f32x4){0.f, 0.f, 0.f, 0.f};
    }

    for (int ks = 0; ks < 8; ++ks) {
        bf16x8 a0 = *(const bf16x8*)(A0 + ks * 512);
        bf16x8 a1 = *(const bf16x8*)(A1 + ks * 512);
#pragma unroll
        for (int t = 0; t < 16; ++t) {
            bf16x8 b = *(const bf16x8*)(B + (ks * 16 + t) * 512);
            acc0[t] = __builtin_amdgcn_mfma_f32_16x16x32_bf16(a0, b, acc0[t], 0, 0, 0);
            acc1[t] = __builtin_amdgcn_mfma_f32_16x16x32_bf16(a1, b, acc1[t], 0, 0, 0);
        }
    }

    int fidx = lane & 15;
    int rsub = (lane >> 4) * 4;              // C/D: row = rsub+i, col = fidx
    int rbase0 = wg * 32 + rsub;
#pragma unroll
    for (int t = 0; t < 16; ++t) {
        int col = t * 16 + fidx;
        float b = bias[col];
#pragma unroll
        for (int i = 0; i < 4; ++i) {
            float v0 = acc0[t][i] + b;
            float v1 = acc1[t][i] + b;
            out[(size_t)(rbase0 + i) * DIM + col] = v0 > 0.f ? v0 : expm1f(v0);
            out[(size_t)(rbase0 + 16 + i) * DIM + col] = v1 > 0.f ? v1 : expm1f(v1);
        }
    }
}

extern "C" void kernel_launch(void* const* d_in, const int* in_sizes, int n_in,
                              void* d_out, int out_size, void* d_ws, size_t ws_size,
                              hipStream_t stream) {
    const float* h    = (const float*)d_in[0];
    const float* W    = (const float*)d_in[1];
    const float* bias = (const float*)d_in[2];
    const int*   src  = (const int*)d_in[3];
    const int*   dst  = (const int*)d_in[4];
    float* out = (float*)d_out;

    if (ws_size < WS_NEED) return;  // insufficient scratch -> loud failure

    char* w = (char*)d_ws;
    int* outd = (int*)w;
    int* ind  = outd + NA;
    int* rowp = outd + 2 * NA;
    int* cnt  = outd + 3 * NA;
    int* bsum = outd + 4 * NA;
    int* csr  = outd + CSR_IOFF;
    unsigned short* hs  = (unsigned short*)(w + HS_OFF);
    unsigned short* wtp = (unsigned short*)(w + WT_OFF);
    unsigned short* Ap  = (unsigned short*)(w + AGG_OFF);

    hipMemsetAsync(outd, 0, (size_t)2 * NA * sizeof(int), stream);  // outd+ind
    hipMemsetAsync(cnt, 0, (size_t)NA * sizeof(int), stream);

    k_deg<<<NE / 256, 256, 0, stream>>>(src, dst, outd, ind);
    k_scan1<<<SCAN_NB, 1024, 0, stream>>>(ind, rowp, bsum);
    k_scan2<<<1, 128, 0, stream>>>(bsum);
    k_scan3<<<SCAN_NB, 1024, 0, stream>>>(rowp, bsum);
    k_fill<<<NE / 256, 256, 0, stream>>>(src, dst, rowp, cnt, csr);
    k_hscale<<<(NN * (DIM / 4)) / 256, 256, 0, stream>>>(h, outd, hs);
    k_wt2<<<(DIM * DIM) / 256, 256, 0, stream>>>(W, wtp);
    k_agg<<<(NN + 3) / 4, 256, 0, stream>>>(hs, csr, rowp, ind, Ap);
    k_gemm<<<(NN / 32 + 3) / 4, 256, 0, stream>>>(Ap, wtp, bias, out);
}

// Round 8
// 458.117 us; speedup vs baseline: 1.2106x; 1.0579x over previous
//
#include <hip/hip_runtime.h>
#include <cstdint>
#include <cstddef>

#define NN 100000
#define NE 1600000
#define DIM 256

// workspace layout (ints)
#define NA 100352            // NN rounded up, 4B ints
#define CSR_IOFF (4*NA + 512)
// byte offsets for bf16 regions
#define HS_OFF   8007680ull                     // (CSR_IOFF + NE) * 4
#define WT_OFF   (HS_OFF + (size_t)NN*DIM*2)    // weight packed, 128 KB
#define AGG_OFF  (WT_OFF + (size_t)DIM*DIM*2)   // A fragment-packed, 51.2 MB
#define WS_NEED  (AGG_OFF + (size_t)NN*DIM*2)

typedef short bf16x8 __attribute__((ext_vector_type(8)));
typedef float f32x4 __attribute__((ext_vector_type(4)));
typedef unsigned short u16x4 __attribute__((ext_vector_type(4)));

__device__ __forceinline__ float bf2f(unsigned short u) {
    return __uint_as_float(((unsigned)u) << 16);
}
__device__ __forceinline__ unsigned short f2bf(float f) {
    unsigned u = __float_as_uint(f);
    u += 0x7FFF + ((u >> 16) & 1);   // round-to-nearest-even
    return (unsigned short)(u >> 16);
}

// ---- degree histograms -----------------------------------------------------
__global__ void k_deg(const int* __restrict__ src, const int* __restrict__ dst,
                      int* __restrict__ outd, int* __restrict__ ind) {
    int e = blockIdx.x * blockDim.x + threadIdx.x;
    if (e < NE) {
        atomicAdd(&outd[src[e]], 1);
        atomicAdd(&ind[dst[e]], 1);
    }
}

// ---- 3-kernel exclusive prefix scan of in_deg -> row_ptr -------------------
#define SCAN_NB 98   // ceil(NN/1024)

__global__ void k_scan1(const int* __restrict__ ind, int* __restrict__ rowp,
                        int* __restrict__ bsum) {
    __shared__ int tmp[1024];
    int t = threadIdx.x;
    int i = blockIdx.x * 1024 + t;
    int x = (i < NN) ? ind[i] : 0;
    tmp[t] = x;
    __syncthreads();
    for (int off = 1; off < 1024; off <<= 1) {
        int v = (t >= off) ? tmp[t - off] : 0;
        __syncthreads();
        tmp[t] += v;
        __syncthreads();
    }
    if (i < NN) rowp[i] = tmp[t] - x;           // exclusive within block
    if (t == 1023) bsum[blockIdx.x] = tmp[t];   // block total
}

__global__ void k_scan2(int* __restrict__ bsum) {
    __shared__ int tmp[128];
    int t = threadIdx.x;
    int x = (t < SCAN_NB) ? bsum[t] : 0;
    tmp[t] = x;
    __syncthreads();
    for (int off = 1; off < 128; off <<= 1) {
        int v = (t >= off) ? tmp[t - off] : 0;
        __syncthreads();
        tmp[t] += v;
        __syncthreads();
    }
    if (t < SCAN_NB) bsum[t] = tmp[t] - x;      // exclusive
}

__global__ void k_scan3(int* __restrict__ rowp, const int* __restrict__ bsum) {
    int i = blockIdx.x * 1024 + threadIdx.x;
    if (i < NN) rowp[i] += bsum[blockIdx.x];
    if (i == 0) rowp[NN] = NE;
}

// ---- CSR fill (sorted-by-dst edge array of src indices) --------------------
__global__ void k_fill(const int* __restrict__ src, const int* __restrict__ dst,
                       const int* __restrict__ rowp, int* __restrict__ cnt,
                       int* __restrict__ csr) {
    int e = blockIdx.x * blockDim.x + threadIdx.x;
    if (e < NE) {
        int d = dst[e];
        int p = rowp[d] + atomicAdd(&cnt[d], 1);
        csr[p] = src[e];
    }
}

// ---- h_scaled = bf16(h * rsqrt(max(out_deg,1))) ----------------------------
__global__ void k_hscale(const float* __restrict__ h, const int* __restrict__ outd,
                         unsigned short* __restrict__ hs) {
    int i = blockIdx.x * blockDim.x + threadIdx.x;   // chunk of 4 floats
    if (i >= NN * (DIM / 4)) return;
    int node = i >> 6;                                // DIM/4 = 64 chunks/node
    float s = rsqrtf(fmaxf((float)outd[node], 1.0f));
    float4 v = ((const float4*)h)[i];
    u16x4 o;
    o.x = f2bf(v.x * s);
    o.y = f2bf(v.y * s);
    o.z = f2bf(v.z * s);
    o.w = f2bf(v.w * s);
    ((u16x4*)hs)[i] = o;
}

// ---- weight -> bf16, MFMA-fragment-packed ----------------------------------
// wtp element p: j=p&7, l=(p>>3)&63, t=(p>>9)&15, ks=p>>13
//   holds W[k = ks*32 + (l>>4)*8 + j][col = t*16 + (l&15)]
__global__ void k_wt2(const float* __restrict__ W, unsigned short* __restrict__ wtp) {
    int p = blockIdx.x * blockDim.x + threadIdx.x;   // 0..65535
    int j = p & 7, l = (p >> 3) & 63, t = (p >> 9) & 15, ks = p >> 13;
    int k = ks * 32 + (l >> 4) * 8 + j;
    int col = t * 16 + (l & 15);
    wtp[p] = f2bf(W[k * DIM + col]);
}

// ---- pull aggregation -> A written MFMA-fragment-packed --------------------
// Ap frag (g, ks) at elements (g*8+ks)*512; lane l holds
//   A[row = g*16 + (l&15)][k = ks*32 + (l>>4)*8 + j], j=0..7
// 4-edge unroll: 4 row-gathers (2 KB) in flight per wave for latency hiding.
__global__ __launch_bounds__(256) void k_agg(const unsigned short* __restrict__ hs,
                                             const int* __restrict__ csr,
                                             const int* __restrict__ rowp,
                                             const int* __restrict__ ind,
                                             unsigned short* __restrict__ Ap) {
    int wave = threadIdx.x >> 6;
    int lane = threadIdx.x & 63;
    int node = blockIdx.x * 4 + wave;
    if (node >= NN) return;
    int e0 = rowp[node], e1 = rowp[node + 1];
    float a0 = 0.f, a1 = 0.f, a2 = 0.f, a3 = 0.f;
    int e = e0;
    for (; e + 3 < e1; e += 4) {
        int s0 = __builtin_nontemporal_load(csr + e);
        int s1 = __builtin_nontemporal_load(csr + e + 1);
        int s2 = __builtin_nontemporal_load(csr + e + 2);
        int s3 = __builtin_nontemporal_load(csr + e + 3);
        u16x4 u0 = ((const u16x4*)(hs + (size_t)s0 * DIM))[lane];
        u16x4 u1 = ((const u16x4*)(hs + (size_t)s1 * DIM))[lane];
        u16x4 u2 = ((const u16x4*)(hs + (size_t)s2 * DIM))[lane];
        u16x4 u3 = ((const u16x4*)(hs + (size_t)s3 * DIM))[lane];
        a0 += (bf2f(u0.x) + bf2f(u1.x)) + (bf2f(u2.x) + bf2f(u3.x));
        a1 += (bf2f(u0.y) + bf2f(u1.y)) + (bf2f(u2.y) + bf2f(u3.y));
        a2 += (bf2f(u0.z) + bf2f(u1.z)) + (bf2f(u2.z) + bf2f(u3.z));
        a3 += (bf2f(u0.w) + bf2f(u1.w)) + (bf2f(u2.w) + bf2f(u3.w));
    }
    for (; e < e1; ++e) {
        int s0 = __builtin_nontemporal_load(csr + e);
        u16x4 u = ((const u16x4*)(hs + (size_t)s0 * DIM))[lane];
        a0 += bf2f(u.x);
        a1 += bf2f(u.y);
        a2 += bf2f(u.z);
        a3 += bf2f(u.w);
    }
    float nd = rsqrtf(fmaxf((float)ind[node], 1.0f));
    u16x4 o;
    o.x = f2bf(a0 * nd);
    o.y = f2bf(a1 * nd);
    o.z = f2bf(a2 * nd);
    o.w = f2bf(a3 * nd);
    // fragment-packed scatter: this lane's 4 elements are k = 4*lane .. 4*lane+3
    int g = node >> 4, fidx = node & 15;
    int ks = lane >> 3;              // (4*lane)>>5
    int kgrp = (lane >> 1) & 3;      // ((4*lane)&31)>>3
    int j0 = (lane & 1) * 4;         // (4*lane)&7
    size_t pidx = ((size_t)(g * 8 + ks) * 64 + kgrp * 16 + fidx) * 8 + j0;
    __builtin_nontemporal_store(o, (u16x4*)(Ap + pidx));  // streaming, never re-read here
}

// ---- GEMM: out = ELU(Ap @ Bp + bias), both operands fragment-packed --------
// 1 wave = 16 rows x 256 cols; acc 64 VGPR -> ~2x occupancy vs 32-row tile.
// 6250 waves, no A duplication (row split), B (128 KB) L2-resident.
__global__ __launch_bounds__(256) void k_gemm(const unsigned short* __restrict__ Ap,
                                              const unsigned short* __restrict__ Bp,
                                              const float* __restrict__ bias,
                                              float* __restrict__ out) {
    int wave = threadIdx.x >> 6;
    int lane = threadIdx.x & 63;
    int g = blockIdx.x * 4 + wave;           // 16-row group id
    if (g >= NN / 16) return;                // 6250 groups exactly

    const short* A = (const short*)Ap + (size_t)g * 4096 + lane * 8;
    const short* B = (const short*)Bp + lane * 8;

    f32x4 acc[16];
#pragma unroll
    for (int t = 0; t < 16; ++t) acc[t] = (f32x4){0.f, 0.f, 0.f, 0.f};

    for (int ks = 0; ks < 8; ++ks) {
        bf16x8 a = *(const bf16x8*)(A + ks * 512);
#pragma unroll
        for (int t = 0; t < 16; ++t) {
            bf16x8 b = *(const bf16x8*)(B + (ks * 16 + t) * 512);
            acc[t] = __builtin_amdgcn_mfma_f32_16x16x32_bf16(a, b, acc[t], 0, 0, 0);
        }
    }

    int fidx = lane & 15;
    int rsub = (lane >> 4) * 4;              // C/D: row = rsub+i, col = fidx
    int rbase = g * 16 + rsub;
#pragma unroll
    for (int t = 0; t < 16; ++t) {
        int col = t * 16 + fidx;
        float b = bias[col];
#pragma unroll
        for (int i = 0; i < 4; ++i) {
            float v = acc[t][i] + b;
            v = v > 0.f ? v : expm1f(v);
            __builtin_nontemporal_store(v, &out[(size_t)(rbase + i) * DIM + col]);
        }
    }
}

extern "C" void kernel_launch(void* const* d_in, const int* in_sizes, int n_in,
                              void* d_out, int out_size, void* d_ws, size_t ws_size,
                              hipStream_t stream) {
    const float* h    = (const float*)d_in[0];
    const float* W    = (const float*)d_in[1];
    const float* bias = (const float*)d_in[2];
    const int*   src  = (const int*)d_in[3];
    const int*   dst  = (const int*)d_in[4];
    float* out = (float*)d_out;

    if (ws_size < WS_NEED) return;  // insufficient scratch -> loud failure

    char* w = (char*)d_ws;
    int* outd = (int*)w;
    int* ind  = outd + NA;
    int* rowp = outd + 2 * NA;
    int* cnt  = outd + 3 * NA;
    int* bsum = outd + 4 * NA;
    int* csr  = outd + CSR_IOFF;
    unsigned short* hs  = (unsigned short*)(w + HS_OFF);
    unsigned short* wtp = (unsigned short*)(w + WT_OFF);
    unsigned short* Ap  = (unsigned short*)(w + AGG_OFF);

    hipMemsetAsync(outd, 0, (size_t)2 * NA * sizeof(int), stream);  // outd+ind
    hipMemsetAsync(cnt, 0, (size_t)NA * sizeof(int), stream);

    k_deg<<<NE / 256, 256, 0, stream>>>(src, dst, outd, ind);
    k_scan1<<<SCAN_NB, 1024, 0, stream>>>(ind, rowp, bsum);
    k_scan2<<<1, 128, 0, stream>>>(bsum);
    k_scan3<<<SCAN_NB, 1024, 0, stream>>>(rowp, bsum);
    k_fill<<<NE / 256, 256, 0, stream>>>(src, dst, rowp, cnt, csr);
    k_hscale<<<(NN * (DIM / 4)) / 256, 256, 0, stream>>>(h, outd, hs);
    k_wt2<<<(DIM * DIM) / 256, 256, 0, stream>>>(W, wtp);
    k_agg<<<(NN + 3) / 4, 256, 0, stream>>>(hs, csr, rowp, ind, Ap);
    k_gemm<<<(NN / 16 + 3) / 4, 256, 0, stream>>>(Ap, wtp, bias, out);
}

// Round 9
// 455.525 us; speedup vs baseline: 1.2175x; 1.0057x over previous
//
#include <hip/hip_runtime.h>
#include <cstdint>
#include <cstddef>

#define NN 100000
#define NE 1600000
#define DIM 256

// workspace layout (ints)
#define NA 100352            // NN rounded up, 4B ints
#define CSR_IOFF (4*NA + 512)
// byte offsets for bf16 regions
#define HS_OFF   8007680ull                     // (CSR_IOFF + NE) * 4
#define WT_OFF   (HS_OFF + (size_t)NN*DIM*2)    // weight packed, 128 KB
#define WS_NEED  (WT_OFF + (size_t)DIM*DIM*2)

typedef short bf16x8 __attribute__((ext_vector_type(8)));
typedef float f32x4 __attribute__((ext_vector_type(4)));
typedef unsigned short u16x4 __attribute__((ext_vector_type(4)));

__device__ __forceinline__ float bf2f(unsigned short u) {
    return __uint_as_float(((unsigned)u) << 16);
}
__device__ __forceinline__ unsigned short f2bf(float f) {
    unsigned u = __float_as_uint(f);
    u += 0x7FFF + ((u >> 16) & 1);   // round-to-nearest-even
    return (unsigned short)(u >> 16);
}

// ---- degree histograms -----------------------------------------------------
__global__ void k_deg(const int* __restrict__ src, const int* __restrict__ dst,
                      int* __restrict__ outd, int* __restrict__ ind) {
    int e = blockIdx.x * blockDim.x + threadIdx.x;
    if (e < NE) {
        atomicAdd(&outd[src[e]], 1);
        atomicAdd(&ind[dst[e]], 1);
    }
}

// ---- 3-kernel exclusive prefix scan of in_deg -> row_ptr -------------------
#define SCAN_NB 98   // ceil(NN/1024)

__global__ void k_scan1(const int* __restrict__ ind, int* __restrict__ rowp,
                        int* __restrict__ bsum) {
    __shared__ int tmp[1024];
    int t = threadIdx.x;
    int i = blockIdx.x * 1024 + t;
    int x = (i < NN) ? ind[i] : 0;
    tmp[t] = x;
    __syncthreads();
    for (int off = 1; off < 1024; off <<= 1) {
        int v = (t >= off) ? tmp[t - off] : 0;
        __syncthreads();
        tmp[t] += v;
        __syncthreads();
    }
    if (i < NN) rowp[i] = tmp[t] - x;           // exclusive within block
    if (t == 1023) bsum[blockIdx.x] = tmp[t];   // block total
}

__global__ void k_scan2(int* __restrict__ bsum) {
    __shared__ int tmp[128];
    int t = threadIdx.x;
    int x = (t < SCAN_NB) ? bsum[t] : 0;
    tmp[t] = x;
    __syncthreads();
    for (int off = 1; off < 128; off <<= 1) {
        int v = (t >= off) ? tmp[t - off] : 0;
        __syncthreads();
        tmp[t] += v;
        __syncthreads();
    }
    if (t < SCAN_NB) bsum[t] = tmp[t] - x;      // exclusive
}

// writes rowp and a working copy (cnt) used as the atomic fill cursor
__global__ void k_scan3(int* __restrict__ rowp, const int* __restrict__ bsum,
                        int* __restrict__ cnt) {
    int i = blockIdx.x * 1024 + threadIdx.x;
    if (i < NN) {
        int v = rowp[i] + bsum[blockIdx.x];
        rowp[i] = v;
        cnt[i] = v;
    }
    if (i == 0) rowp[NN] = NE;
}

// ---- CSR fill (sorted-by-dst edge array of src indices) --------------------
__global__ void k_fill(const int* __restrict__ src, const int* __restrict__ dst,
                       int* __restrict__ cnt, int* __restrict__ csr) {
    int e = blockIdx.x * blockDim.x + threadIdx.x;
    if (e < NE) {
        int p = atomicAdd(&cnt[dst[e]], 1);   // cnt pre-seeded with rowp
        csr[p] = src[e];
    }
}

// ---- h_scaled = bf16(h * rsqrt(max(out_deg,1))) ----------------------------
__global__ void k_hscale(const float* __restrict__ h, const int* __restrict__ outd,
                         unsigned short* __restrict__ hs) {
    int i = blockIdx.x * blockDim.x + threadIdx.x;   // chunk of 4 floats
    if (i >= NN * (DIM / 4)) return;
    int node = i >> 6;                                // DIM/4 = 64 chunks/node
    float s = rsqrtf(fmaxf((float)outd[node], 1.0f));
    float4 v = ((const float4*)h)[i];
    u16x4 o;
    o.x = f2bf(v.x * s);
    o.y = f2bf(v.y * s);
    o.z = f2bf(v.z * s);
    o.w = f2bf(v.w * s);
    ((u16x4*)hs)[i] = o;
}

// ---- weight -> bf16, MFMA-fragment-packed ----------------------------------
// wtp element p: j=p&7, l=(p>>3)&63, t=(p>>9)&15, ks=p>>13
//   holds W[k = ks*32 + (l>>4)*8 + j][col = t*16 + (l&15)]
__global__ void k_wt2(const float* __restrict__ W, unsigned short* __restrict__ wtp) {
    int p = blockIdx.x * blockDim.x + threadIdx.x;   // 0..65535
    int j = p & 7, l = (p >> 3) & 63, t = (p >> 9) & 15, ks = p >> 13;
    int k = ks * 32 + (l >> 4) * 8 + j;
    int col = t * 16 + (l & 15);
    wtp[p] = f2bf(W[k * DIM + col]);
}

// ---- FUSED aggregate + GEMM + bias + ELU -----------------------------------
// Block = 256 thr = 4 waves, owns 16 nodes (rows).
// Phase 1: wave w aggregates nodes nb+4w..nb+4w+3 (4-deep edge gather),
//          scales by rsqrt(in_deg), writes bf16 row into LDS As[r][.].
// Phase 2: wave w computes cols [64w, 64w+64) of out for the 16 rows:
//          8 ks-steps x 4 col-frags MFMA, A from LDS, B from packed wtp (L2).
// LDS row padded to 264 shorts: phase-1 writes linear; phase-2 frag reads
// start at bank (4r+4q+16ks)%32 -> 8 lanes per 4-bank window = floor rate.
__global__ __launch_bounds__(256) void k_aggemm(const unsigned short* __restrict__ hs,
                                                const int* __restrict__ csr,
                                                const int* __restrict__ rowp,
                                                const int* __restrict__ ind,
                                                const unsigned short* __restrict__ wtp,
                                                const float* __restrict__ bias,
                                                float* __restrict__ out) {
    __shared__ short As[16][264];
    int wave = threadIdx.x >> 6;
    int lane = threadIdx.x & 63;
    int nb = blockIdx.x * 16;

    // ---- phase 1: aggregate 4 nodes per wave ----
    for (int i = 0; i < 4; ++i) {
        int r = wave * 4 + i;
        int node = nb + r;
        int e0 = rowp[node], e1 = rowp[node + 1];
        float a0 = 0.f, a1 = 0.f, a2 = 0.f, a3 = 0.f;
        int e = e0;
        for (; e + 3 < e1; e += 4) {
            int s0 = __builtin_nontemporal_load(csr + e);
            int s1 = __builtin_nontemporal_load(csr + e + 1);
            int s2 = __builtin_nontemporal_load(csr + e + 2);
            int s3 = __builtin_nontemporal_load(csr + e + 3);
            u16x4 u0 = ((const u16x4*)(hs + (size_t)s0 * DIM))[lane];
            u16x4 u1 = ((const u16x4*)(hs + (size_t)s1 * DIM))[lane];
            u16x4 u2 = ((const u16x4*)(hs + (size_t)s2 * DIM))[lane];
            u16x4 u3 = ((const u16x4*)(hs + (size_t)s3 * DIM))[lane];
            a0 += (bf2f(u0.x) + bf2f(u1.x)) + (bf2f(u2.x) + bf2f(u3.x));
            a1 += (bf2f(u0.y) + bf2f(u1.y)) + (bf2f(u2.y) + bf2f(u3.y));
            a2 += (bf2f(u0.z) + bf2f(u1.z)) + (bf2f(u2.z) + bf2f(u3.z));
            a3 += (bf2f(u0.w) + bf2f(u1.w)) + (bf2f(u2.w) + bf2f(u3.w));
        }
        for (; e < e1; ++e) {
            int s0 = __builtin_nontemporal_load(csr + e);
            u16x4 u = ((const u16x4*)(hs + (size_t)s0 * DIM))[lane];
            a0 += bf2f(u.x);
            a1 += bf2f(u.y);
            a2 += bf2f(u.z);
            a3 += bf2f(u.w);
        }
        float nd = rsqrtf(fmaxf((float)ind[node], 1.0f));
        u16x4 o;
        o.x = f2bf(a0 * nd);
        o.y = f2bf(a1 * nd);
        o.z = f2bf(a2 * nd);
        o.w = f2bf(a3 * nd);
        *(u16x4*)&As[r][4 * lane] = o;   // linear across lanes: conflict-free
    }
    __syncthreads();

    // ---- phase 2: 16x256 GEMM quadrant per wave ----
    const short* B = (const short*)wtp + lane * 8;
    f32x4 acc[4];
#pragma unroll
    for (int tt = 0; tt < 4; ++tt) acc[tt] = (f32x4){0.f, 0.f, 0.f, 0.f};

    int fr = lane & 15;      // A-row / C-col fragment index
    int q  = lane >> 4;      // k-group / C-row group
    for (int ks = 0; ks < 8; ++ks) {
        bf16x8 a = *(const bf16x8*)&As[fr][ks * 32 + q * 8];
#pragma unroll
        for (int tt = 0; tt < 4; ++tt) {
            int t = wave * 4 + tt;
            bf16x8 b = *(const bf16x8*)(B + (size_t)(ks * 16 + t) * 512);
            acc[tt] = __builtin_amdgcn_mfma_f32_16x16x32_bf16(a, b, acc[tt], 0, 0, 0);
        }
    }

    // ---- epilogue: bias + ELU + store ----
    int rbase = nb + q * 4;
#pragma unroll
    for (int tt = 0; tt < 4; ++tt) {
        int col = wave * 64 + tt * 16 + fr;
        float bv = bias[col];
#pragma unroll
        for (int i = 0; i < 4; ++i) {
            float v = acc[tt][i] + bv;
            v = v > 0.f ? v : expm1f(v);
            __builtin_nontemporal_store(v, &out[(size_t)(rbase + i) * DIM + col]);
        }
    }
}

extern "C" void kernel_launch(void* const* d_in, const int* in_sizes, int n_in,
                              void* d_out, int out_size, void* d_ws, size_t ws_size,
                              hipStream_t stream) {
    const float* h    = (const float*)d_in[0];
    const float* W    = (const float*)d_in[1];
    const float* bias = (const float*)d_in[2];
    const int*   src  = (const int*)d_in[3];
    const int*   dst  = (const int*)d_in[4];
    float* out = (float*)d_out;

    if (ws_size < WS_NEED) return;  // insufficient scratch -> loud failure

    char* w = (char*)d_ws;
    int* outd = (int*)w;
    int* ind  = outd + NA;
    int* rowp = outd + 2 * NA;
    int* cnt  = outd + 3 * NA;
    int* bsum = outd + 4 * NA;
    int* csr  = outd + CSR_IOFF;
    unsigned short* hs  = (unsigned short*)(w + HS_OFF);
    unsigned short* wtp = (unsigned short*)(w + WT_OFF);

    hipMemsetAsync(outd, 0, (size_t)2 * NA * sizeof(int), stream);  // outd+ind

    k_deg<<<NE / 256, 256, 0, stream>>>(src, dst, outd, ind);
    k_scan1<<<SCAN_NB, 1024, 0, stream>>>(ind, rowp, bsum);
    k_scan2<<<1, 128, 0, stream>>>(bsum);
    k_scan3<<<SCAN_NB, 1024, 0, stream>>>(rowp, bsum, cnt);
    k_fill<<<NE / 256, 256, 0, stream>>>(src, dst, cnt, csr);
    k_hscale<<<(NN * (DIM / 4)) / 256, 256, 0, stream>>>(h, outd, hs);
    k_wt2<<<(DIM * DIM) / 256, 256, 0, stream>>>(W, wtp);
    k_aggemm<<<NN / 16, 256, 0, stream>>>(hs, csr, rowp, ind, wtp, bias, out);
}